// Round 1
// baseline (1166.587 us; speedup 1.0000x reference)
//
#include <hip/hip_runtime.h>
#include <cstdint>
#include <cstddef>

typedef unsigned short u16;
typedef __attribute__((ext_vector_type(8))) short bf16x8;   // 8 bf16 = 4 VGPRs
typedef __attribute__((ext_vector_type(4))) float f32x4;    // MFMA accumulator

#define DEVFN static __device__ __forceinline__

DEVFN u16 f2bf(float f) {
  unsigned u = __float_as_uint(f);
  unsigned r = (u + 0x7FFFu + ((u >> 16) & 1u)) >> 16;   // RTN-even
  return (u16)r;
}

// async global->LDS, 16B/lane. LDS dest = wave-uniform base + lane*16 (m104/m108).
DEVFN void gload16(const void* g, void* l) {
  __builtin_amdgcn_global_load_lds(
      (const __attribute__((address_space(1))) void*)g,
      (__attribute__((address_space(3))) void*)l, 16, 0, 0);
}

// ---------------- merged prep: converts + wqkv row-permute + cos/sin table ----------------
// wqkv q/k rows interleaved per head: d<64 -> 2d, d>=64 -> 2(d-64)+1  (QK^T invariant).
// cs[l*64+m] = (cos(l,m), sin(l,m))
__global__ void prep(const float* __restrict__ x, const float* __restrict__ wqkv,
                     const float* __restrict__ wout, const float* __restrict__ cosp,
                     const float* __restrict__ sinp, u16* __restrict__ xb,
                     u16* __restrict__ wqkvb, u16* __restrict__ woutb,
                     float2* __restrict__ cs) {
  constexpr int X4 = 4194304;      // x elems/4
  constexpr int W4 = 3145728;      // wqkv elems/4
  constexpr int O4 = 1048576;      // wout elems/4
  int i = blockIdx.x * blockDim.x + threadIdx.x;
  if (i < X4) {
    float4 v = ((const float4*)x)[i];
    unsigned long long w = (unsigned long long)f2bf(v.x)
        | ((unsigned long long)f2bf(v.y) << 16)
        | ((unsigned long long)f2bf(v.z) << 32)
        | ((unsigned long long)f2bf(v.w) << 48);
    *(unsigned long long*)(xb + (size_t)i * 4) = w;
  } else if (i < X4 + W4) {
    int j = i - X4;
    int base = j * 4;
    int e = base >> 11, col = base & 2047;
    int e2;
    if (e < 4096) {
      int part = e >> 11, loc = e & 2047;
      int h = loc >> 7, d = loc & 127;
      int d2 = (d < 64) ? 2 * d : 2 * (d - 64) + 1;
      e2 = part * 2048 + h * 128 + d2;
    } else {
      e2 = e;                      // v rows unpermuted
    }
    float4 v = *(const float4*)&wqkv[(size_t)base];
    unsigned long long w = (unsigned long long)f2bf(v.x)
        | ((unsigned long long)f2bf(v.y) << 16)
        | ((unsigned long long)f2bf(v.z) << 32)
        | ((unsigned long long)f2bf(v.w) << 48);
    *(unsigned long long*)(wqkvb + (size_t)e2 * 2048 + col) = w;
  } else if (i < X4 + W4 + O4) {
    int j = i - X4 - W4;
    float4 v = ((const float4*)wout)[j];
    unsigned long long w = (unsigned long long)f2bf(v.x)
        | ((unsigned long long)f2bf(v.y) << 16)
        | ((unsigned long long)f2bf(v.z) << 32)
        | ((unsigned long long)f2bf(v.w) << 48);
    *(unsigned long long*)(woutb + (size_t)j * 4) = w;
  } else {
    int k = i - X4 - W4 - O4;      // < 32768
    int ld4 = k * 4;
#pragma unroll
    for (int u = 0; u < 4; u++) {
      int ld = ld4 + u;
      int l = ld >> 6, d = ld & 63;
      cs[ld] = make_float2(cosp[(size_t)l * 128 + d], sinp[(size_t)l * 128 + d]);
    }
  }
}

// ---------------- bf16 GEMM core: C[M,N] = A[M,K] * Bt[N,K]^T, fused epilogues ----------------
// 128x128 tile, BK=32, 4 waves (2x2), wave 64x64 (4x4 MFMA). m97 staging via gload16,
// unpadded LDS rows + chunk XOR swizzle -> 2-way bank alias only (free, m136).
enum { M_F32OUT = 0, M_ROPE = 1, M_VT = 2 };

template <int MODE>
DEVFN void gemm_core(const u16* __restrict__ A, const u16* __restrict__ Bt,
                     void* __restrict__ Cv, const float2* __restrict__ cs,
                     int N, int K, int m0, int n0, u16* As, u16* Bs) {
  int tid = threadIdx.x;
  int wv = tid >> 6, lane = tid & 63, quad = lane >> 4, l16 = lane & 15;
  int wm = (wv >> 1) * 64, wn = (wv & 1) * 64;
  f32x4 acc[4][4] = {};
  int r0 = wv * 16 + (lane >> 2);
  int r1 = r0 + 64;
  int c0 = (lane & 3) ^ ((r0 >> 1) & 3);
  int c1 = (lane & 3) ^ ((r1 >> 1) & 3);
  const u16* Ap0 = A + (size_t)(m0 + r0) * K + c0 * 8;
  const u16* Ap1 = A + (size_t)(m0 + r1) * K + c1 * 8;
  const u16* Bp0 = Bt + (size_t)(n0 + r0) * K + c0 * 8;
  const u16* Bp1 = Bt + (size_t)(n0 + r1) * K + c1 * 8;
  u16* As0 = &As[(wv * 16) * 32];
  u16* As1 = &As[(wv * 16 + 64) * 32];
  u16* Bs0 = &Bs[(wv * 16) * 32];
  u16* Bs1 = &Bs[(wv * 16 + 64) * 32];
  for (int k0 = 0; k0 < K; k0 += 32) {
    __syncthreads();
    gload16(Ap0, As0);
    gload16(Ap1, As1);
    gload16(Bp0, Bs0);
    gload16(Bp1, Bs1);
    Ap0 += 32; Ap1 += 32; Bp0 += 32; Bp1 += 32;
    __syncthreads();
    bf16x8 af[4], bf[4];
#pragma unroll
    for (int i = 0; i < 4; i++) {
      int r = wm + i * 16 + l16;
      af[i] = *(const bf16x8*)&As[r * 32 + ((quad ^ ((r >> 1) & 3)) << 3)];
    }
#pragma unroll
    for (int j = 0; j < 4; j++) {
      int r = wn + j * 16 + l16;
      bf[j] = *(const bf16x8*)&Bs[r * 32 + ((quad ^ ((r >> 1) & 3)) << 3)];
    }
#pragma unroll
    for (int i = 0; i < 4; i++)
#pragma unroll
      for (int j = 0; j < 4; j++) {
        if (MODE == M_VT)
          acc[i][j] = __builtin_amdgcn_mfma_f32_16x16x32_bf16(bf[j], af[i], acc[i][j], 0, 0, 0);
        else
          acc[i][j] = __builtin_amdgcn_mfma_f32_16x16x32_bf16(af[i], bf[j], acc[i][j], 0, 0, 0);
      }
  }
  // C/D layout: col = lane&15, row = quad*4 + reg  (m89/m91 verified)
  if (MODE == M_F32OUT) {
    float* C = (float*)Cv;
#pragma unroll
    for (int i = 0; i < 4; i++)
#pragma unroll
      for (int r = 0; r < 4; r++) {
        size_t row = (size_t)(m0 + wm + i * 16 + quad * 4 + r);
#pragma unroll
        for (int j = 0; j < 4; j++)
          C[row * N + (n0 + wn + j * 16 + l16)] = acc[i][j][r];
      }
  } else if (MODE == M_ROPE) {
    constexpr float QSCALE = 1.4426950408889634f * 0.08838834764831845f;
    const float scale = (n0 >> 11) ? 1.0f : QSCALE;   // q gets log2e/sqrt(128)
    u16* C = (u16*)Cv;
#pragma unroll
    for (int i = 0; i < 4; i++)
#pragma unroll
      for (int r = 0; r < 4; r++) {
        int row = m0 + wm + i * 16 + quad * 4 + r;
        int l = row & 2047;
#pragma unroll
        for (int j = 0; j < 4; j++) {
          int col = n0 + wn + j * 16 + l16;
          int dm = (col & 127) >> 1;
          float2 csv = cs[l * 64 + dm];
          float v = acc[i][j][r];
          float pv = __shfl_xor(v, 1);                 // partner lane (col^1)
          float sg = (l16 & 1) ? csv.y : -csv.y;       // even: -sin, odd: +sin
          C[(size_t)row * 4096 + col] = f2bf((v * csv.x + pv * sg) * scale);
        }
      }
  } else {
    // VT: acc holds C^T tiles; row = v-channel, col = token. Store vt[bh][d][l].
    u16* vt = (u16*)Cv;
#pragma unroll
    for (int j = 0; j < 4; j++)
#pragma unroll
      for (int r = 0; r < 4; r++) {
        int vch = n0 + wn + j * 16 + quad * 4 + r;     // 0..2047
        int h = vch >> 7, d = vch & 127;
#pragma unroll
        for (int i = 0; i < 4; i++) {
          int token = m0 + wm + i * 16 + l16;
          int b = token >> 11, lloc = token & 2047;
          vt[((size_t)(b * 16 + h)) * 262144 + (size_t)d * 2048 + lloc] =
              f2bf(acc[i][j][r]);
        }
      }
  }
}

// Merged QKV GEMM: bx<32 -> RoPE epilogue into qkv (stride 4096); bx>=32 -> V^T.
// 1-D grid with XCD y-striping: each XCD owns an 8-row stripe of M (A rows L2-resident).
__global__ __launch_bounds__(256) void gemm_qkv(const u16* __restrict__ xb,
                                                const u16* __restrict__ wqkvb,
                                                u16* __restrict__ qkvo,
                                                u16* __restrict__ vto,
                                                const float2* __restrict__ cs) {
  __shared__ u16 As[128 * 32];
  __shared__ u16 Bs[128 * 32];
  int id = blockIdx.x;
  int xcd = id & 7, sub = id >> 3;      // sub 0..383
  int bx = sub % 48, by = xcd * 8 + sub / 48;
  if (bx < 32)
    gemm_core<M_ROPE>(xb, wqkvb, qkvo, cs, 0, 2048, by * 128, bx * 128, As, Bs);
  else
    gemm_core<M_VT>(xb, wqkvb + (size_t)4096 * 2048, vto, nullptr, 0, 2048,
                    by * 128, (bx - 32) * 128, As, Bs);
}

__global__ __launch_bounds__(256) void gemm_out_k(const u16* __restrict__ A,
                                                  const u16* __restrict__ Bt,
                                                  float* __restrict__ C) {
  __shared__ u16 As[128 * 32];
  __shared__ u16 Bs[128 * 32];
  int id = blockIdx.x;
  int xcd = id & 7, sub = id >> 3;      // sub 0..127
  int bx = sub % 16, by = xcd * 8 + sub / 16;
  gemm_core<M_F32OUT>(A, Bt, C, nullptr, 2048, 2048, by * 128, bx * 128, As, Bs);
}

// ---------------- fused flash attention (fixed-base softmax, no online max) ----------------
// R5: 256 thr = 4 waves, 32 Q-rows/wave. Rationale: attn was LDS-read-BW bound
// (each wave reads the full 32KB K + 32KB V tile per kt; 16 rows/wave = low reuse).
// 32 rows/wave halves K/V LDS traffic per Q-row: each bfr/vf fragment read feeds
// TWO row-tiles of MFMA. Acc = s[2][8]+o[2][8] = 128 VGPRs; fits because 4-wave
// blocks at 2 blk/CU = 2 waves/SIMD -> 256-VGPR budget (R4's 8-wave/32-row variant
// spilled at the 128-VGPR budget of 4 waves/SIMD).
// XCD swizzle: all 16 qtiles of one bh on one XCD -> K/V served from L2.
// LDS rows = 256B, chunk XOR swizzle -> 2-way bank alias (free, m136).
DEVFN int swz(int row, int chunk) { return row * 128 + ((chunk ^ (row & 15)) << 3); }

__global__ __launch_bounds__(256, 2) void attn_fused(const u16* __restrict__ qkv,
                                                     const u16* __restrict__ vt,
                                                     u16* __restrict__ out) {
  __shared__ u16 Ksm[128 * 128];
  __shared__ u16 Vsm[128 * 128];
  int tid = threadIdx.x;
  int wv = tid >> 6, lane = tid & 63, quad = lane >> 4, l16 = lane & 15;
  int id = blockIdx.x;
  int xcd = id & 7, sub = id >> 3;             // sub 0..127
  int bh = ((sub >> 4) << 3) | xcd;            // 8 bh per XCD, all 16 qtiles local
  int qt = sub & 15;
  int b = bh >> 4, h = bh & 15;
  const u16* qptr = qkv + (size_t)b * 2048 * 4096 + h * 128;
  const u16* kptr = qptr + 2048;
  const u16* vptr = vt + (size_t)bh * 262144;
  int q0 = qt * 128;

  int rofs = lane >> 4;      // 0..3 (row within a 4-row gload group)
  int scc = lane & 15;       // LDS slot-chunk

  // stage all 128 Q rows through Ksm via global_load_lds, pull A-fragments to regs
#pragma unroll
  for (int j = 0; j < 8; j++) {
    int rb = j * 16 + wv * 4;
    int r = rb + rofs;
    int ck = scc ^ (r & 15);
    gload16(&qptr[(size_t)(q0 + r) * 4096 + ck * 8], &Ksm[rb * 128]);
  }
  __syncthreads();
  bf16x8 qf[2][4];
#pragma unroll
  for (int i = 0; i < 2; i++)
#pragma unroll
    for (int ks = 0; ks < 4; ks++)
      qf[i][ks] = *(const bf16x8*)&Ksm[swz(wv * 32 + i * 16 + l16, ks * 4 + quad)];

  f32x4 o[2][8] = {};
  float l[2][4] = {{0.f, 0.f, 0.f, 0.f}, {0.f, 0.f, 0.f, 0.f}};

  for (int kt = 0; kt < 16; kt++) {
    __syncthreads();                       // prior-iteration LDS reads drained
    int kk0 = kt * 128;
#pragma unroll
    for (int j = 0; j < 8; j++) {
      int rb = j * 16 + wv * 4;
      int r = rb + rofs;
      int ck = scc ^ (r & 15);
      gload16(&kptr[(size_t)(kk0 + r) * 4096 + ck * 8], &Ksm[rb * 128]);
      gload16(&vptr[(size_t)r * 2048 + kk0 + ck * 8], &Vsm[rb * 128]);
    }
    __syncthreads();
    // S = Q K^T (scores already in log2 domain via QSCALE folded into q).
    // One bfr read feeds both row-tiles (the LDS-traffic halving).
    f32x4 s[2][8] = {};
#pragma unroll
    for (int ks = 0; ks < 4; ks++) {
#pragma unroll
      for (int nt = 0; nt < 8; nt++) {
        bf16x8 bfr = *(const bf16x8*)&Ksm[swz(nt * 16 + l16, ks * 4 + quad)];
        s[0][nt] = __builtin_amdgcn_mfma_f32_16x16x32_bf16(qf[0][ks], bfr, s[0][nt], 0, 0, 0);
        s[1][nt] = __builtin_amdgcn_mfma_f32_16x16x32_bf16(qf[1][ks], bfr, s[1][nt], 0, 0, 0);
      }
    }
    // fixed-base softmax: p = exp2(s); lane-local row-sum accumulation only
#pragma unroll
    for (int i = 0; i < 2; i++)
#pragma unroll
      for (int nt = 0; nt < 8; nt++)
#pragma unroll
        for (int r = 0; r < 4; r++) {
          float p = exp2f(s[i][nt][r]);
          s[i][nt][r] = p;
          l[i][r] += p;
        }
    __syncthreads();                       // all waves done reading K from Ksm
    // P (C-layout) -> Ksm in A-operand layout position (same-wave rows; no extra barrier)
#pragma unroll
    for (int i = 0; i < 2; i++)
#pragma unroll
      for (int nt = 0; nt < 8; nt++)
#pragma unroll
        for (int r = 0; r < 4; r++) {
          int row = wv * 32 + i * 16 + quad * 4 + r;
          int col = nt * 16 + l16;
          Ksm[swz(row, col >> 3) + (col & 7)] = f2bf(s[i][nt][r]);
        }
    // O += P V  (Vsm holds V^T per head: rows = d, cols = keys).
    // One vf read feeds both row-tiles.
#pragma unroll
    for (int ks = 0; ks < 4; ks++) {
      bf16x8 pf0 = *(const bf16x8*)&Ksm[swz(wv * 32 + l16, ks * 4 + quad)];
      bf16x8 pf1 = *(const bf16x8*)&Ksm[swz(wv * 32 + 16 + l16, ks * 4 + quad)];
#pragma unroll
      for (int nt = 0; nt < 8; nt++) {
        bf16x8 vf = *(const bf16x8*)&Vsm[swz(nt * 16 + l16, ks * 4 + quad)];
        o[0][nt] = __builtin_amdgcn_mfma_f32_16x16x32_bf16(pf0, vf, o[0][nt], 0, 0, 0);
        o[1][nt] = __builtin_amdgcn_mfma_f32_16x16x32_bf16(pf1, vf, o[1][nt], 0, 0, 0);
      }
    }
  }
  // epilogue: reduce l across the 16 col-lanes once, divide, store bf16
#pragma unroll
  for (int i = 0; i < 2; i++)
#pragma unroll
    for (int r = 0; r < 4; r++)
#pragma unroll
      for (int off = 1; off < 16; off <<= 1) l[i][r] += __shfl_xor(l[i][r], off, 16);
  u16* obase = out + ((size_t)b * 2048 + q0) * 2048 + h * 128;
#pragma unroll
  for (int i = 0; i < 2; i++)
#pragma unroll
    for (int r = 0; r < 4; r++) {
      float inv = 1.0f / l[i][r];
      int row = wv * 32 + i * 16 + quad * 4 + r;
#pragma unroll
      for (int nt = 0; nt < 8; nt++)
        obase[(size_t)row * 2048 + nt * 16 + l16] = f2bf(o[i][nt][r] * inv);
    }
}

// ---------------- launch ----------------
extern "C" void kernel_launch(void* const* d_in, const int* in_sizes, int n_in,
                              void* d_out, int out_size, void* d_ws, size_t ws_size,
                              hipStream_t stream) {
  const float* x    = (const float*)d_in[0];   // [4,2048,2048]
  const float* cosp = (const float*)d_in[1];   // [2048,128]
  const float* sinp = (const float*)d_in[2];   // [2048,128]
  const float* wqkv = (const float*)d_in[3];   // [6144,2048]
  const float* wout = (const float*)d_in[4];   // [2048,2048]
  float* outp = (float*)d_out;                 // [4,2048,2048] fp32

  u16* ws    = (u16*)d_ws;
  u16* xb    = ws;                     // 16,777,216 elems (dead after gemm_qkv; reused)
  u16* wqkvb = xb + 16777216;          // 12,582,912 (row-permuted q/k)
  u16* woutb = wqkvb + 12582912;       //  4,194,304
  u16* qkv   = woutb + 4194304;        // 33,554,432 (q,k only; row stride 4096)
  u16* vt    = qkv + 33554432;         // 16,777,216
  float2* cs = (float2*)(vt + 16777216); // 131,072 float2 = 1 MB
  u16* attn  = xb;                     // alias: xb dead after gemm_qkv

  prep<<<32896, 256, 0, stream>>>(x, wqkv, wout, cosp, sinp, xb, wqkvb, woutb, cs);
  gemm_qkv<<<3072, 256, 0, stream>>>(xb, wqkvb, qkv, vt, cs);
  attn_fused<<<1024, 256, 0, stream>>>(qkv, vt, attn);
  gemm_out_k<<<1024, 256, 0, stream>>>(attn, woutb, outp);
}

// Round 2
// 707.178 us; speedup vs baseline: 1.6496x; 1.6496x over previous
//
#include <hip/hip_runtime.h>
#include <cstdint>
#include <cstddef>

typedef unsigned short u16;
typedef __attribute__((ext_vector_type(8))) short bf16x8;   // 8 bf16 = 4 VGPRs
typedef __attribute__((ext_vector_type(4))) float f32x4;    // MFMA accumulator

#define DEVFN static __device__ __forceinline__

DEVFN u16 f2bf(float f) {
  unsigned u = __float_as_uint(f);
  unsigned r = (u + 0x7FFFu + ((u >> 16) & 1u)) >> 16;   // RTN-even
  return (u16)r;
}

// async global->LDS, 16B/lane. LDS dest = wave-uniform base + lane*16 (m104/m108).
DEVFN void gload16(const void* g, void* l) {
  __builtin_amdgcn_global_load_lds(
      (const __attribute__((address_space(1))) void*)g,
      (__attribute__((address_space(3))) void*)l, 16, 0, 0);
}

// ---------------- merged prep: converts + wqkv row-permute + cos/sin table ----------------
// wqkv q/k rows interleaved per head: d<64 -> 2d, d>=64 -> 2(d-64)+1  (QK^T invariant).
// cs[l*64+m] = (cos(l,m), sin(l,m))
__global__ void prep(const float* __restrict__ x, const float* __restrict__ wqkv,
                     const float* __restrict__ wout, const float* __restrict__ cosp,
                     const float* __restrict__ sinp, u16* __restrict__ xb,
                     u16* __restrict__ wqkvb, u16* __restrict__ woutb,
                     float2* __restrict__ cs) {
  constexpr int X4 = 4194304;      // x elems/4
  constexpr int W4 = 3145728;      // wqkv elems/4
  constexpr int O4 = 1048576;      // wout elems/4
  int i = blockIdx.x * blockDim.x + threadIdx.x;
  if (i < X4) {
    float4 v = ((const float4*)x)[i];
    unsigned long long w = (unsigned long long)f2bf(v.x)
        | ((unsigned long long)f2bf(v.y) << 16)
        | ((unsigned long long)f2bf(v.z) << 32)
        | ((unsigned long long)f2bf(v.w) << 48);
    *(unsigned long long*)(xb + (size_t)i * 4) = w;
  } else if (i < X4 + W4) {
    int j = i - X4;
    int base = j * 4;
    int e = base >> 11, col = base & 2047;
    int e2;
    if (e < 4096) {
      int part = e >> 11, loc = e & 2047;
      int h = loc >> 7, d = loc & 127;
      int d2 = (d < 64) ? 2 * d : 2 * (d - 64) + 1;
      e2 = part * 2048 + h * 128 + d2;
    } else {
      e2 = e;                      // v rows unpermuted
    }
    float4 v = *(const float4*)&wqkv[(size_t)base];
    unsigned long long w = (unsigned long long)f2bf(v.x)
        | ((unsigned long long)f2bf(v.y) << 16)
        | ((unsigned long long)f2bf(v.z) << 32)
        | ((unsigned long long)f2bf(v.w) << 48);
    *(unsigned long long*)(wqkvb + (size_t)e2 * 2048 + col) = w;
  } else if (i < X4 + W4 + O4) {
    int j = i - X4 - W4;
    float4 v = ((const float4*)wout)[j];
    unsigned long long w = (unsigned long long)f2bf(v.x)
        | ((unsigned long long)f2bf(v.y) << 16)
        | ((unsigned long long)f2bf(v.z) << 32)
        | ((unsigned long long)f2bf(v.w) << 48);
    *(unsigned long long*)(woutb + (size_t)j * 4) = w;
  } else {
    int k = i - X4 - W4 - O4;      // < 32768
    int ld4 = k * 4;
#pragma unroll
    for (int u = 0; u < 4; u++) {
      int ld = ld4 + u;
      int l = ld >> 6, d = ld & 63;
      cs[ld] = make_float2(cosp[(size_t)l * 128 + d], sinp[(size_t)l * 128 + d]);
    }
  }
}

// ---------------- bf16 GEMM core: C[M,N] = A[M,K] * Bt[N,K]^T, fused epilogues ----------------
// 128x128 tile, BK=32, 4 waves (2x2), wave 64x64 (4x4 MFMA). m97 staging via gload16,
// unpadded LDS rows + chunk XOR swizzle -> 2-way bank alias only (free, m136).
enum { M_F32OUT = 0, M_ROPE = 1, M_VT = 2 };

template <int MODE>
DEVFN void gemm_core(const u16* __restrict__ A, const u16* __restrict__ Bt,
                     void* __restrict__ Cv, const float2* __restrict__ cs,
                     int N, int K, int m0, int n0, u16* As, u16* Bs) {
  int tid = threadIdx.x;
  int wv = tid >> 6, lane = tid & 63, quad = lane >> 4, l16 = lane & 15;
  int wm = (wv >> 1) * 64, wn = (wv & 1) * 64;
  f32x4 acc[4][4] = {};
  int r0 = wv * 16 + (lane >> 2);
  int r1 = r0 + 64;
  int c0 = (lane & 3) ^ ((r0 >> 1) & 3);
  int c1 = (lane & 3) ^ ((r1 >> 1) & 3);
  const u16* Ap0 = A + (size_t)(m0 + r0) * K + c0 * 8;
  const u16* Ap1 = A + (size_t)(m0 + r1) * K + c1 * 8;
  const u16* Bp0 = Bt + (size_t)(n0 + r0) * K + c0 * 8;
  const u16* Bp1 = Bt + (size_t)(n0 + r1) * K + c1 * 8;
  u16* As0 = &As[(wv * 16) * 32];
  u16* As1 = &As[(wv * 16 + 64) * 32];
  u16* Bs0 = &Bs[(wv * 16) * 32];
  u16* Bs1 = &Bs[(wv * 16 + 64) * 32];
  for (int k0 = 0; k0 < K; k0 += 32) {
    __syncthreads();
    gload16(Ap0, As0);
    gload16(Ap1, As1);
    gload16(Bp0, Bs0);
    gload16(Bp1, Bs1);
    Ap0 += 32; Ap1 += 32; Bp0 += 32; Bp1 += 32;
    __syncthreads();
    bf16x8 af[4], bf[4];
#pragma unroll
    for (int i = 0; i < 4; i++) {
      int r = wm + i * 16 + l16;
      af[i] = *(const bf16x8*)&As[r * 32 + ((quad ^ ((r >> 1) & 3)) << 3)];
    }
#pragma unroll
    for (int j = 0; j < 4; j++) {
      int r = wn + j * 16 + l16;
      bf[j] = *(const bf16x8*)&Bs[r * 32 + ((quad ^ ((r >> 1) & 3)) << 3)];
    }
#pragma unroll
    for (int i = 0; i < 4; i++)
#pragma unroll
      for (int j = 0; j < 4; j++) {
        if (MODE == M_VT)
          acc[i][j] = __builtin_amdgcn_mfma_f32_16x16x32_bf16(bf[j], af[i], acc[i][j], 0, 0, 0);
        else
          acc[i][j] = __builtin_amdgcn_mfma_f32_16x16x32_bf16(af[i], bf[j], acc[i][j], 0, 0, 0);
      }
  }
  // C/D layout: col = lane&15, row = quad*4 + reg  (m89/m91 verified)
  if (MODE == M_F32OUT) {
    float* C = (float*)Cv;
#pragma unroll
    for (int i = 0; i < 4; i++)
#pragma unroll
      for (int r = 0; r < 4; r++) {
        size_t row = (size_t)(m0 + wm + i * 16 + quad * 4 + r);
#pragma unroll
        for (int j = 0; j < 4; j++)
          C[row * N + (n0 + wn + j * 16 + l16)] = acc[i][j][r];
      }
  } else if (MODE == M_ROPE) {
    constexpr float QSCALE = 1.4426950408889634f * 0.08838834764831845f;
    const float scale = (n0 >> 11) ? 1.0f : QSCALE;   // q gets log2e/sqrt(128)
    u16* C = (u16*)Cv;
#pragma unroll
    for (int i = 0; i < 4; i++)
#pragma unroll
      for (int r = 0; r < 4; r++) {
        int row = m0 + wm + i * 16 + quad * 4 + r;
        int l = row & 2047;
#pragma unroll
        for (int j = 0; j < 4; j++) {
          int col = n0 + wn + j * 16 + l16;
          int dm = (col & 127) >> 1;
          float2 csv = cs[l * 64 + dm];
          float v = acc[i][j][r];
          float pv = __shfl_xor(v, 1);                 // partner lane (col^1)
          float sg = (l16 & 1) ? csv.y : -csv.y;       // even: -sin, odd: +sin
          C[(size_t)row * 4096 + col] = f2bf((v * csv.x + pv * sg) * scale);
        }
      }
  } else {
    // VT: acc holds C^T tiles; row = v-channel, col = token. Store vt[bh][d][l].
    u16* vt = (u16*)Cv;
#pragma unroll
    for (int j = 0; j < 4; j++)
#pragma unroll
      for (int r = 0; r < 4; r++) {
        int vch = n0 + wn + j * 16 + quad * 4 + r;     // 0..2047
        int h = vch >> 7, d = vch & 127;
#pragma unroll
        for (int i = 0; i < 4; i++) {
          int token = m0 + wm + i * 16 + l16;
          int b = token >> 11, lloc = token & 2047;
          vt[((size_t)(b * 16 + h)) * 262144 + (size_t)d * 2048 + lloc] =
              f2bf(acc[i][j][r]);
        }
      }
  }
}

// Merged QKV GEMM: bx<32 -> RoPE epilogue into qkv (stride 4096); bx>=32 -> V^T.
// 1-D grid with XCD y-striping: each XCD owns an 8-row stripe of M (A rows L2-resident).
__global__ __launch_bounds__(256) void gemm_qkv(const u16* __restrict__ xb,
                                                const u16* __restrict__ wqkvb,
                                                u16* __restrict__ qkvo,
                                                u16* __restrict__ vto,
                                                const float2* __restrict__ cs) {
  __shared__ u16 As[128 * 32];
  __shared__ u16 Bs[128 * 32];
  int id = blockIdx.x;
  int xcd = id & 7, sub = id >> 3;      // sub 0..383
  int bx = sub % 48, by = xcd * 8 + sub / 48;
  if (bx < 32)
    gemm_core<M_ROPE>(xb, wqkvb, qkvo, cs, 0, 2048, by * 128, bx * 128, As, Bs);
  else
    gemm_core<M_VT>(xb, wqkvb + (size_t)4096 * 2048, vto, nullptr, 0, 2048,
                    by * 128, (bx - 32) * 128, As, Bs);
}

__global__ __launch_bounds__(256) void gemm_out_k(const u16* __restrict__ A,
                                                  const u16* __restrict__ Bt,
                                                  float* __restrict__ C) {
  __shared__ u16 As[128 * 32];
  __shared__ u16 Bs[128 * 32];
  int id = blockIdx.x;
  int xcd = id & 7, sub = id >> 3;      // sub 0..127
  int bx = sub % 16, by = xcd * 8 + sub / 16;
  gemm_core<M_F32OUT>(A, Bt, C, nullptr, 2048, 2048, by * 128, bx * 128, As, Bs);
}

// ---------------- fused flash attention (fixed-base softmax, no online max) ----------------
// R6: R0's verified 512-thr/8-wave/16-rows-per-wave compute structure (R5's 256-thr
// variant halved waves/CU -> L2 thrash, reverted), with the staging/sync restructured:
//   KVBLK=64, double-buffered K (2x16KB) + V (2x16KB) + DEDICATED P buffer (16KB)
//   = 80KB LDS -> still 2 blk/CU, 16 waves/CU.
// One __syncthreads per kt: its auto vmcnt(0) drains loads issued a FULL ITERATION ago
// (free), prefetch kt+1 issues right after the barrier, and the private P buffer removes
// R0's "done reading K" barrier (P write/read are same-wave rows, separate region).
// Barriers: 48 -> 32, every drain warm. Layouts identical to R0 (verified).
DEVFN int swz(int row, int chunk)   { return row * 128 + ((chunk ^ (row & 15)) << 3); } // 256B rows
DEVFN int swz64(int row, int chunk) { return row * 64  + ((chunk ^ (row & 7)) << 3); }  // 128B rows

__global__ __launch_bounds__(512) void attn_fused(const u16* __restrict__ qkv,
                                                  const u16* __restrict__ vt,
                                                  u16* __restrict__ out) {
  // S layout (u16 units): [0,8192)=Kb0  [8192,16384)=Kb1
  //                       [16384,24576)=Vb0 [24576,32768)=Vb1  [32768,40960)=P
  __shared__ u16 S[40960];                     // 80 KB
  u16* const Pb = S + 32768;
  int tid = threadIdx.x;
  int wv = tid >> 6, lane = tid & 63, quad = lane >> 4, l16 = lane & 15;
  int id = blockIdx.x;
  int xcd = id & 7, sub = id >> 3;             // sub 0..127
  int bh = ((sub >> 4) << 3) | xcd;            // 8 bh per XCD, all 16 qtiles local
  int qt = sub & 15;
  int b = bh >> 4, h = bh & 15;
  const u16* qptr = qkv + (size_t)b * 2048 * 4096 + h * 128;
  const u16* kptr = qptr + 2048;
  const u16* vptr = vt + (size_t)bh * 262144;
  int q0 = qt * 128;

  // ---- Q staging: 128 rows x 256B through S[0..16384), then pull to regs ----
#pragma unroll
  for (int j = 0; j < 4; j++) {
    int rb = wv * 4 + j * 32;
    int r = rb + (lane >> 4);
    int ck = (lane & 15) ^ (r & 15);
    gload16(&qptr[(size_t)(q0 + r) * 4096 + ck * 8], &S[rb * 128]);
  }
  __syncthreads();
  bf16x8 qf[4];
#pragma unroll
  for (int ks = 0; ks < 4; ks++)
    qf[ks] = *(const bf16x8*)&S[swz(wv * 16 + l16, ks * 4 + quad)];
  __syncthreads();                             // qf reads done before kt=0 staging

  f32x4 o[8] = {};
  float l[4] = {0.f, 0.f, 0.f, 0.f};

  // prologue: stage kt=0 into Kb0/Vb0 (K: 64 rows x 256B; V: 128 rows x 128B)
#pragma unroll
  for (int j = 0; j < 2; j++) {
    int rbk = wv * 4 + j * 32;
    int rk = rbk + (lane >> 4);
    int ckk = (lane & 15) ^ (rk & 15);
    gload16(&kptr[(size_t)rk * 4096 + ckk * 8], &S[rbk * 128]);
    int rbv = wv * 8 + j * 64;
    int rv = rbv + (lane >> 3);
    int ckv = (lane & 7) ^ (rv & 7);
    gload16(&vptr[(size_t)rv * 2048 + ckv * 8], &S[16384 + rbv * 64]);
  }

  for (int kt = 0; kt < 32; kt++) {
    int cur = kt & 1;
    const u16* Kc = S + cur * 8192;
    const u16* Vc = S + 16384 + cur * 8192;
    __syncthreads();   // auto vmcnt(0): drains cur-tile loads (1 iter old) + prior reads
    if (kt < 31) {     // prefetch kt+1 into the other buffer set
      int kk0 = (kt + 1) * 64;
      u16* kb = S + (cur ^ 1) * 8192;
      u16* vb = S + 16384 + (cur ^ 1) * 8192;
#pragma unroll
      for (int j = 0; j < 2; j++) {
        int rbk = wv * 4 + j * 32;
        int rk = rbk + (lane >> 4);
        int ckk = (lane & 15) ^ (rk & 15);
        gload16(&kptr[(size_t)(kk0 + rk) * 4096 + ckk * 8], &kb[rbk * 128]);
        int rbv = wv * 8 + j * 64;
        int rv = rbv + (lane >> 3);
        int ckv = (lane & 7) ^ (rv & 7);
        gload16(&vptr[(size_t)rv * 2048 + kk0 + ckv * 8], &vb[rbv * 64]);
      }
    }
    // S = Q K^T (scores in log2 domain via QSCALE folded into q)
    f32x4 s[4] = {};
#pragma unroll
    for (int ks = 0; ks < 4; ks++) {
#pragma unroll
      for (int nt = 0; nt < 4; nt++) {
        bf16x8 bfr = *(const bf16x8*)&Kc[swz(nt * 16 + l16, ks * 4 + quad)];
        s[nt] = __builtin_amdgcn_mfma_f32_16x16x32_bf16(qf[ks], bfr, s[nt], 0, 0, 0);
      }
    }
    // fixed-base softmax: p = exp2(s); lane-local row-sum; P -> private buffer
    // (own-wave rows only: no barrier needed between write and pf read)
#pragma unroll
    for (int nt = 0; nt < 4; nt++)
#pragma unroll
      for (int r = 0; r < 4; r++) {
        float p = exp2f(s[nt][r]);
        l[r] += p;
        int row = wv * 16 + quad * 4 + r;
        int col = nt * 16 + l16;
        Pb[swz64(row, col >> 3) + (col & 7)] = f2bf(p);
      }
    // O += P V  (Vc holds V^T: rows = d, cols = 64 keys)
#pragma unroll
    for (int ks = 0; ks < 2; ks++) {
      bf16x8 pf = *(const bf16x8*)&Pb[swz64(wv * 16 + l16, ks * 4 + quad)];
#pragma unroll
      for (int nt = 0; nt < 8; nt++) {
        bf16x8 vf = *(const bf16x8*)&Vc[swz64(nt * 16 + l16, ks * 4 + quad)];
        o[nt] = __builtin_amdgcn_mfma_f32_16x16x32_bf16(pf, vf, o[nt], 0, 0, 0);
      }
    }
  }
  // epilogue: reduce l across the 16 col-lanes once, divide, store bf16
#pragma unroll
  for (int r = 0; r < 4; r++)
#pragma unroll
    for (int off = 1; off < 16; off <<= 1) l[r] += __shfl_xor(l[r], off, 16);
  u16* obase = out + ((size_t)b * 2048 + q0) * 2048 + h * 128;
#pragma unroll
  for (int r = 0; r < 4; r++) {
    float inv = 1.0f / l[r];
    int row = wv * 16 + quad * 4 + r;
#pragma unroll
    for (int nt = 0; nt < 8; nt++)
      obase[(size_t)row * 2048 + nt * 16 + l16] = f2bf(o[nt][r] * inv);
  }
}

// ---------------- launch ----------------
extern "C" void kernel_launch(void* const* d_in, const int* in_sizes, int n_in,
                              void* d_out, int out_size, void* d_ws, size_t ws_size,
                              hipStream_t stream) {
  const float* x    = (const float*)d_in[0];   // [4,2048,2048]
  const float* cosp = (const float*)d_in[1];   // [2048,128]
  const float* sinp = (const float*)d_in[2];   // [2048,128]
  const float* wqkv = (const float*)d_in[3];   // [6144,2048]
  const float* wout = (const float*)d_in[4];   // [2048,2048]
  float* outp = (float*)d_out;                 // [4,2048,2048] fp32

  u16* ws    = (u16*)d_ws;
  u16* xb    = ws;                     // 16,777,216 elems (dead after gemm_qkv; reused)
  u16* wqkvb = xb + 16777216;          // 12,582,912 (row-permuted q/k)
  u16* woutb = wqkvb + 12582912;       //  4,194,304
  u16* qkv   = woutb + 4194304;        // 33,554,432 (q,k only; row stride 4096)
  u16* vt    = qkv + 33554432;         // 16,777,216
  float2* cs = (float2*)(vt + 16777216); // 131,072 float2 = 1 MB
  u16* attn  = xb;                     // alias: xb dead after gemm_qkv

  prep<<<32896, 256, 0, stream>>>(x, wqkv, wout, cosp, sinp, xb, wqkvb, woutb, cs);
  gemm_qkv<<<3072, 256, 0, stream>>>(xb, wqkvb, qkv, vt, cs);
  attn_fused<<<1024, 512, 0, stream>>>(qkv, vt, attn);
  gemm_out_k<<<1024, 256, 0, stream>>>(attn, woutb, outp);
}

// Round 4
// 664.358 us; speedup vs baseline: 1.7560x; 1.0645x over previous
//
#include <hip/hip_runtime.h>
#include <cstdint>
#include <cstddef>

typedef unsigned short u16;
typedef __attribute__((ext_vector_type(8))) short bf16x8;   // 8 bf16 = 4 VGPRs
typedef __attribute__((ext_vector_type(4))) float f32x4;    // MFMA accumulator

#define DEVFN static __device__ __forceinline__

DEVFN u16 f2bf(float f) {
  unsigned u = __float_as_uint(f);
  unsigned r = (u + 0x7FFFu + ((u >> 16) & 1u)) >> 16;   // RTN-even
  return (u16)r;
}

// async global->LDS, 16B/lane. LDS dest = wave-uniform base + lane*16 (m104/m108).
DEVFN void gload16(const void* g, void* l) {
  __builtin_amdgcn_global_load_lds(
      (const __attribute__((address_space(1))) void*)g,
      (__attribute__((address_space(3))) void*)l, 16, 0, 0);
}

// counted waits + raw barrier (compiler memory fences keep LDS ops ordered)
#define WAITVM(n) asm volatile("s_waitcnt vmcnt(" #n ")" ::: "memory")
#define BARRIER() do { asm volatile("" ::: "memory"); \
                       __builtin_amdgcn_s_barrier();   \
                       asm volatile("" ::: "memory"); } while (0)

// ---------------- merged prep: converts + wqkv row-permute + cos/sin table ----------------
// wqkv q/k rows interleaved per head: d<64 -> 2d, d>=64 -> 2(d-64)+1  (QK^T invariant).
// cs[l*64+m] = (cos(l,m), sin(l,m))
__global__ void prep(const float* __restrict__ x, const float* __restrict__ wqkv,
                     const float* __restrict__ wout, const float* __restrict__ cosp,
                     const float* __restrict__ sinp, u16* __restrict__ xb,
                     u16* __restrict__ wqkvb, u16* __restrict__ woutb,
                     float2* __restrict__ cs) {
  constexpr int X4 = 4194304;      // x elems/4
  constexpr int W4 = 3145728;      // wqkv elems/4
  constexpr int O4 = 1048576;      // wout elems/4
  int i = blockIdx.x * blockDim.x + threadIdx.x;
  if (i < X4) {
    float4 v = ((const float4*)x)[i];
    unsigned long long w = (unsigned long long)f2bf(v.x)
        | ((unsigned long long)f2bf(v.y) << 16)
        | ((unsigned long long)f2bf(v.z) << 32)
        | ((unsigned long long)f2bf(v.w) << 48);
    *(unsigned long long*)(xb + (size_t)i * 4) = w;
  } else if (i < X4 + W4) {
    int j = i - X4;
    int base = j * 4;
    int e = base >> 11, col = base & 2047;
    int e2;
    if (e < 4096) {
      int part = e >> 11, loc = e & 2047;
      int h = loc >> 7, d = loc & 127;
      int d2 = (d < 64) ? 2 * d : 2 * (d - 64) + 1;
      e2 = part * 2048 + h * 128 + d2;
    } else {
      e2 = e;                      // v rows unpermuted
    }
    float4 v = *(const float4*)&wqkv[(size_t)base];
    unsigned long long w = (unsigned long long)f2bf(v.x)
        | ((unsigned long long)f2bf(v.y) << 16)
        | ((unsigned long long)f2bf(v.z) << 32)
        | ((unsigned long long)f2bf(v.w) << 48);
    *(unsigned long long*)(wqkvb + (size_t)e2 * 2048 + col) = w;
  } else if (i < X4 + W4 + O4) {
    int j = i - X4 - W4;
    float4 v = ((const float4*)wout)[j];
    unsigned long long w = (unsigned long long)f2bf(v.x)
        | ((unsigned long long)f2bf(v.y) << 16)
        | ((unsigned long long)f2bf(v.z) << 32)
        | ((unsigned long long)f2bf(v.w) << 48);
    *(unsigned long long*)(woutb + (size_t)j * 4) = w;
  } else {
    int k = i - X4 - W4 - O4;      // < 32768
    int ld4 = k * 4;
#pragma unroll
    for (int u = 0; u < 4; u++) {
      int ld = ld4 + u;
      int l = ld >> 6, d = ld & 63;
      cs[ld] = make_float2(cosp[(size_t)l * 128 + d], sinp[(size_t)l * 128 + d]);
    }
  }
}

// ================= 256x256 8-phase GEMM core (T3+T4+T5 on verified layouts) ==============
// BM=BN=256, BK=64, 512 thr = 8 waves (2M x 4N), wave output 128x64 = acc[8][4].
// LDS: A[2][256*64] + B[2][256*64] bf16 = 128 KB, double-buffered by K-tile parity.
// Rows are 64 elems (128B), chunk XOR swizzle key = row&7 (both staged-source and read
// sides -> conflict-free b128 reads, gload_lds-compatible: LDS linear, source pre-swizzled).
// Schedule per K-tile t (4 phases), staging tile t+1 one tile ahead:
//   ph1: issue B(t+1,h0)[2 ops]  vmcnt(5)  bar  read Ball+Aq0, 16 MFMA
//   ph2: issue B(t+1,h1)[2]      vmcnt(6)  bar  read Aq1,      16 MFMA
//   ph3: issue Aq0,Aq1(t+1)[2]   vmcnt(7)  bar  read Aq2,      16 MFMA
//   ph4: issue Aq2,Aq3(t+1)[2]   vmcnt(8)  bar  read Aq3,      16 MFMA
// Ledger (per-wave outstanding VMEM ops) verified steady-state; loads never drain to 0.
// Last tile peeled with vmcnt 3/2/1/0 and no issues.
enum { M_F32OUT = 0, M_ROPE = 1, M_VT = 2 };

DEVFN bf16x8 rdfrag(const u16* buf, int row, int chunk) {
  return *(const bf16x8*)&buf[row * 64 + (((chunk ^ (row & 7)) & 7) << 3)];
}

template <int MODE, int Q>
DEVFN void phase_mfma(const u16* Ac, const u16* Bc, int wm, int wn, int quad, int l16,
                      bf16x8 (&bfr)[4][2], f32x4 (&acc)[8][4]) {
  if (Q == 0) {
#pragma unroll
    for (int j = 0; j < 4; j++)
#pragma unroll
      for (int kk = 0; kk < 2; kk++)
        bfr[j][kk] = rdfrag(Bc, wn * 64 + j * 16 + l16, kk * 4 + quad);
  }
  bf16x8 af[2][2];
#pragma unroll
  for (int i2 = 0; i2 < 2; i2++)
#pragma unroll
    for (int kk = 0; kk < 2; kk++)
      af[i2][kk] = rdfrag(Ac, wm * 128 + (Q * 2 + i2) * 16 + l16, kk * 4 + quad);
  __builtin_amdgcn_s_setprio(1);
#pragma unroll
  for (int kk = 0; kk < 2; kk++)
#pragma unroll
    for (int i2 = 0; i2 < 2; i2++)
#pragma unroll
      for (int j = 0; j < 4; j++) {
        if (MODE == M_VT)
          acc[Q * 2 + i2][j] = __builtin_amdgcn_mfma_f32_16x16x32_bf16(
              bfr[j][kk], af[i2][kk], acc[Q * 2 + i2][j], 0, 0, 0);
        else
          acc[Q * 2 + i2][j] = __builtin_amdgcn_mfma_f32_16x16x32_bf16(
              af[i2][kk], bfr[j][kk], acc[Q * 2 + i2][j], 0, 0, 0);
      }
  __builtin_amdgcn_s_setprio(0);
}

template <int MODE>
DEVFN void gemm256_core(const u16* __restrict__ A, const u16* __restrict__ Bt,
                        void* __restrict__ Cv, const float2* __restrict__ cs,
                        int N, int m0, int n0, u16* As, u16* Bs) {
  int tid = threadIdx.x;
  int wv = tid >> 6, lane = tid & 63, quad = lane >> 4, l16 = lane & 15;
  int wm = wv >> 2, wn = wv & 3;

  // per-thread pre-swizzled global source pointers (advance by k elems per tile)
  const u16* pB[2][2];
  const u16* pA[4];
#pragma unroll
  for (int h = 0; h < 2; h++)
#pragma unroll
    for (int o = 0; o < 2; o++) {
      int r = h * 128 + o * 64 + wv * 8 + (lane >> 3);
      int ck = (lane & 7) ^ (r & 7);
      pB[h][o] = Bt + (size_t)(n0 + r) * 2048 + ck * 8;
    }
#pragma unroll
  for (int q = 0; q < 4; q++) {
    int rb = (wv < 4) ? (q * 32 + wv * 8) : (128 + q * 32 + (wv - 4) * 8);
    int r = rb + (lane >> 3);
    int ck = (lane & 7) ^ (r & 7);
    pA[q] = A + (size_t)(m0 + r) * 2048 + ck * 8;
  }

#define STAGE_B(h, buf, kk) do {                                    \
    int rb0_ = (h) * 128 + wv * 8;                                  \
    gload16(pB[h][0] + (kk), &(buf)[rb0_ * 64]);                    \
    gload16(pB[h][1] + (kk), &(buf)[(rb0_ + 64) * 64]); } while (0)
#define STAGE_A(q, buf, kk) do {                                    \
    int rb_ = ((wv < 4) ? ((q) * 32 + wv * 8)                       \
                        : (128 + (q) * 32 + (wv - 4) * 8));         \
    gload16(pA[q] + (kk), &(buf)[rb_ * 64]); } while (0)

  f32x4 acc[8][4] = {};
  bf16x8 bfr[4][2];

  // prologue: stage tile 0 into buffer 0 (issue order matches the ledger)
  STAGE_B(0, Bs, 0);
  STAGE_B(1, Bs, 0);
  STAGE_A(0, As, 0);
  STAGE_A(1, As, 0);
  STAGE_A(2, As, 0);
  STAGE_A(3, As, 0);

  for (int t = 0; t < 31; t++) {
    const u16* Ac = As + (t & 1) * 16384;
    const u16* Bc = Bs + (t & 1) * 16384;
    u16* An = As + ((t + 1) & 1) * 16384;
    u16* Bn = Bs + ((t + 1) & 1) * 16384;
    int kn = (t + 1) * 64;
    STAGE_B(0, Bn, kn);
    WAITVM(5); BARRIER();
    phase_mfma<MODE, 0>(Ac, Bc, wm, wn, quad, l16, bfr, acc);
    STAGE_B(1, Bn, kn);
    WAITVM(6); BARRIER();
    phase_mfma<MODE, 1>(Ac, Bc, wm, wn, quad, l16, bfr, acc);
    STAGE_A(0, An, kn);
    STAGE_A(1, An, kn);
    WAITVM(7); BARRIER();
    phase_mfma<MODE, 2>(Ac, Bc, wm, wn, quad, l16, bfr, acc);
    STAGE_A(2, An, kn);
    STAGE_A(3, An, kn);
    WAITVM(8); BARRIER();
    phase_mfma<MODE, 3>(Ac, Bc, wm, wn, quad, l16, bfr, acc);
  }
  {  // last tile (parity 1), no prefetch: drain 3/2/1/0
    const u16* Ac = As + 16384;
    const u16* Bc = Bs + 16384;
    WAITVM(3); BARRIER();
    phase_mfma<MODE, 0>(Ac, Bc, wm, wn, quad, l16, bfr, acc);
    WAITVM(2); BARRIER();
    phase_mfma<MODE, 1>(Ac, Bc, wm, wn, quad, l16, bfr, acc);
    WAITVM(1); BARRIER();
    phase_mfma<MODE, 2>(Ac, Bc, wm, wn, quad, l16, bfr, acc);
    WAITVM(0); BARRIER();
    phase_mfma<MODE, 3>(Ac, Bc, wm, wn, quad, l16, bfr, acc);
  }
#undef STAGE_B
#undef STAGE_A

  // ---- epilogue: C/D layout col = lane&15, row = quad*4 + reg (m89/m91 verified) ----
  if (MODE == M_F32OUT) {
    float* C = (float*)Cv;
#pragma unroll
    for (int i = 0; i < 8; i++)
#pragma unroll
      for (int r = 0; r < 4; r++) {
        size_t row = (size_t)(m0 + wm * 128 + i * 16 + quad * 4 + r);
#pragma unroll
        for (int j = 0; j < 4; j++)
          C[row * N + (n0 + wn * 64 + j * 16 + l16)] = acc[i][j][r];
      }
  } else if (MODE == M_ROPE) {
    constexpr float QSCALE = 1.4426950408889634f * 0.08838834764831845f;
    const float scale = (n0 >> 11) ? 1.0f : QSCALE;   // q gets log2e/sqrt(128)
    u16* C = (u16*)Cv;
#pragma unroll
    for (int i = 0; i < 8; i++)
#pragma unroll
      for (int r = 0; r < 4; r++) {
        int row = m0 + wm * 128 + i * 16 + quad * 4 + r;
        int l = row & 2047;
#pragma unroll
        for (int j = 0; j < 4; j++) {
          int col = n0 + wn * 64 + j * 16 + l16;
          int dm = (col & 127) >> 1;
          float2 csv = cs[l * 64 + dm];
          float v = acc[i][j][r];
          float pv = __shfl_xor(v, 1);                 // partner lane (col^1)
          float sg = (l16 & 1) ? csv.y : -csv.y;       // even: -sin, odd: +sin
          C[(size_t)row * 4096 + col] = f2bf((v * csv.x + pv * sg) * scale);
        }
      }
  } else {
    // VT: swapped operands -> acc holds C^T; row = v-channel, col = token. vt[bh][d][l].
    u16* vt = (u16*)Cv;
#pragma unroll
    for (int j = 0; j < 4; j++)
#pragma unroll
      for (int r = 0; r < 4; r++) {
        int vch = n0 + wn * 64 + j * 16 + quad * 4 + r;   // 0..2047
        int h = vch >> 7, d = vch & 127;
#pragma unroll
        for (int i = 0; i < 8; i++) {
          int token = m0 + wm * 128 + i * 16 + l16;
          int b = token >> 11, lloc = token & 2047;
          vt[((size_t)(b * 16 + h)) * 262144 + (size_t)d * 2048 + lloc] =
              f2bf(acc[i][j][r]);
        }
      }
  }
}

// Merged QKV GEMM: bx<16 -> RoPE epilogue into qkv (stride 4096); bx>=16 -> V^T.
// XCD y-striping: each XCD owns a 4-row stripe of M-tiles (A rows L2-resident).
__global__ __launch_bounds__(512, 2) void gemm_qkv(const u16* __restrict__ xb,
                                                   const u16* __restrict__ wqkvb,
                                                   u16* __restrict__ qkvo,
                                                   u16* __restrict__ vto,
                                                   const float2* __restrict__ cs) {
  __shared__ u16 As[32768];
  __shared__ u16 Bs[32768];
  int id = blockIdx.x;
  int xcd = id & 7, sub = id >> 3;      // sub 0..95
  int bx = sub % 24, by = xcd * 4 + sub / 24;
  if (bx < 16)
    gemm256_core<M_ROPE>(xb, wqkvb, qkvo, cs, 0, by * 256, bx * 256, As, Bs);
  else
    gemm256_core<M_VT>(xb, wqkvb + (size_t)4096 * 2048, vto, nullptr, 0,
                       by * 256, (bx - 16) * 256, As, Bs);
}

__global__ __launch_bounds__(512, 2) void gemm_out_k(const u16* __restrict__ A,
                                                     const u16* __restrict__ Bt,
                                                     float* __restrict__ C) {
  __shared__ u16 As[32768];
  __shared__ u16 Bs[32768];
  int id = blockIdx.x;
  int xcd = id & 7, sub = id >> 3;      // sub 0..31
  int bx = sub % 8, by = xcd * 4 + sub / 8;
  gemm256_core<M_F32OUT>(A, Bt, C, nullptr, 2048, by * 256, bx * 256, As, Bs);
}

// ---------------- fused flash attention (fixed-base softmax, no online max) ----------------
// R6 structure (verified): 512 thr / 8 waves / 16 Q-rows per wave; KVBLK=64 with
// double-buffered K (2x16KB) + V (2x16KB) + dedicated P buffer (16KB) = 80KB LDS,
// 2 blk/CU. One __syncthreads per kt (warm vmcnt drain), prefetch right after barrier.
DEVFN int swz(int row, int chunk)   { return row * 128 + ((chunk ^ (row & 15)) << 3); } // 256B rows
DEVFN int swz64(int row, int chunk) { return row * 64  + ((chunk ^ (row & 7)) << 3); }  // 128B rows

__global__ __launch_bounds__(512) void attn_fused(const u16* __restrict__ qkv,
                                                  const u16* __restrict__ vt,
                                                  u16* __restrict__ out) {
  // S layout (u16 units): [0,8192)=Kb0  [8192,16384)=Kb1
  //                       [16384,24576)=Vb0 [24576,32768)=Vb1  [32768,40960)=P
  __shared__ u16 S[40960];                     // 80 KB
  u16* const Pb = S + 32768;
  int tid = threadIdx.x;
  int wv = tid >> 6, lane = tid & 63, quad = lane >> 4, l16 = lane & 15;
  int id = blockIdx.x;
  int xcd = id & 7, sub = id >> 3;             // sub 0..127
  int bh = ((sub >> 4) << 3) | xcd;            // 8 bh per XCD, all 16 qtiles local
  int qt = sub & 15;
  int b = bh >> 4, h = bh & 15;
  const u16* qptr = qkv + (size_t)b * 2048 * 4096 + h * 128;
  const u16* kptr = qptr + 2048;
  const u16* vptr = vt + (size_t)bh * 262144;
  int q0 = qt * 128;

  // ---- Q staging: 128 rows x 256B through S[0..16384), then pull to regs ----
#pragma unroll
  for (int j = 0; j < 4; j++) {
    int rb = wv * 4 + j * 32;
    int r = rb + (lane >> 4);
    int ck = (lane & 15) ^ (r & 15);
    gload16(&qptr[(size_t)(q0 + r) * 4096 + ck * 8], &S[rb * 128]);
  }
  __syncthreads();
  bf16x8 qf[4];
#pragma unroll
  for (int ks = 0; ks < 4; ks++)
    qf[ks] = *(const bf16x8*)&S[swz(wv * 16 + l16, ks * 4 + quad)];
  __syncthreads();                             // qf reads done before kt=0 staging

  f32x4 o[8] = {};
  float l[4] = {0.f, 0.f, 0.f, 0.f};

  // prologue: stage kt=0 into Kb0/Vb0 (K: 64 rows x 256B; V: 128 rows x 128B)
#pragma unroll
  for (int j = 0; j < 2; j++) {
    int rbk = wv * 4 + j * 32;
    int rk = rbk + (lane >> 4);
    int ckk = (lane & 15) ^ (rk & 15);
    gload16(&kptr[(size_t)rk * 4096 + ckk * 8], &S[rbk * 128]);
    int rbv = wv * 8 + j * 64;
    int rv = rbv + (lane >> 3);
    int ckv = (lane & 7) ^ (rv & 7);
    gload16(&vptr[(size_t)rv * 2048 + ckv * 8], &S[16384 + rbv * 64]);
  }

  for (int kt = 0; kt < 32; kt++) {
    int cur = kt & 1;
    const u16* Kc = S + cur * 8192;
    const u16* Vc = S + 16384 + cur * 8192;
    __syncthreads();   // auto vmcnt(0): drains cur-tile loads (1 iter old) + prior reads
    if (kt < 31) {     // prefetch kt+1 into the other buffer set
      int kk0 = (kt + 1) * 64;
      u16* kb = S + (cur ^ 1) * 8192;
      u16* vb = S + 16384 + (cur ^ 1) * 8192;
#pragma unroll
      for (int j = 0; j < 2; j++) {
        int rbk = wv * 4 + j * 32;
        int rk = rbk + (lane >> 4);
        int ckk = (lane & 15) ^ (rk & 15);
        gload16(&kptr[(size_t)(kk0 + rk) * 4096 + ckk * 8], &kb[rbk * 128]);
        int rbv = wv * 8 + j * 64;
        int rv = rbv + (lane >> 3);
        int ckv = (lane & 7) ^ (rv & 7);
        gload16(&vptr[(size_t)rv * 2048 + kk0 + ckv * 8], &vb[rbv * 64]);
      }
    }
    // S = Q K^T (scores in log2 domain via QSCALE folded into q)
    f32x4 s[4] = {};
#pragma unroll
    for (int ks = 0; ks < 4; ks++) {
#pragma unroll
      for (int nt = 0; nt < 4; nt++) {
        bf16x8 bfr = *(const bf16x8*)&Kc[swz(nt * 16 + l16, ks * 4 + quad)];
        s[nt] = __builtin_amdgcn_mfma_f32_16x16x32_bf16(qf[ks], bfr, s[nt], 0, 0, 0);
      }
    }
    // fixed-base softmax: p = exp2(s); lane-local row-sum; P -> private buffer
    // (own-wave rows only: no barrier needed between write and pf read)
#pragma unroll
    for (int nt = 0; nt < 4; nt++)
#pragma unroll
      for (int r = 0; r < 4; r++) {
        float p = exp2f(s[nt][r]);
        l[r] += p;
        int row = wv * 16 + quad * 4 + r;
        int col = nt * 16 + l16;
        Pb[swz64(row, col >> 3) + (col & 7)] = f2bf(p);
      }
    // O += P V  (Vc holds V^T: rows = d, cols = 64 keys)
#pragma unroll
    for (int ks = 0; ks < 2; ks++) {
      bf16x8 pf = *(const bf16x8*)&Pb[swz64(wv * 16 + l16, ks * 4 + quad)];
#pragma unroll
      for (int nt = 0; nt < 8; nt++) {
        bf16x8 vf = *(const bf16x8*)&Vc[swz64(nt * 16 + l16, ks * 4 + quad)];
        o[nt] = __builtin_amdgcn_mfma_f32_16x16x32_bf16(pf, vf, o[nt], 0, 0, 0);
      }
    }
  }
  // epilogue: reduce l across the 16 col-lanes once, divide, store bf16
#pragma unroll
  for (int r = 0; r < 4; r++)
#pragma unroll
    for (int off = 1; off < 16; off <<= 1) l[r] += __shfl_xor(l[r], off, 16);
  u16* obase = out + ((size_t)b * 2048 + q0) * 2048 + h * 128;
#pragma unroll
  for (int r = 0; r < 4; r++) {
    float inv = 1.0f / l[r];
    int row = wv * 16 + quad * 4 + r;
#pragma unroll
    for (int nt = 0; nt < 8; nt++)
      obase[(size_t)row * 2048 + nt * 16 + l16] = f2bf(o[nt][r] * inv);
  }
}

// ---------------- launch ----------------
extern "C" void kernel_launch(void* const* d_in, const int* in_sizes, int n_in,
                              void* d_out, int out_size, void* d_ws, size_t ws_size,
                              hipStream_t stream) {
  const float* x    = (const float*)d_in[0];   // [4,2048,2048]
  const float* cosp = (const float*)d_in[1];   // [2048,128]
  const float* sinp = (const float*)d_in[2];   // [2048,128]
  const float* wqkv = (const float*)d_in[3];   // [6144,2048]
  const float* wout = (const float*)d_in[4];   // [2048,2048]
  float* outp = (float*)d_out;                 // [4,2048,2048] fp32

  u16* ws    = (u16*)d_ws;
  u16* xb    = ws;                     // 16,777,216 elems (dead after gemm_qkv; reused)
  u16* wqkvb = xb + 16777216;          // 12,582,912 (row-permuted q/k)
  u16* woutb = wqkvb + 12582912;       //  4,194,304
  u16* qkv   = woutb + 4194304;        // 33,554,432 (q,k only; row stride 4096)
  u16* vt    = qkv + 33554432;         // 16,777,216
  float2* cs = (float2*)(vt + 16777216); // 131,072 float2 = 1 MB
  u16* attn  = xb;                     // alias: xb dead after gemm_qkv

  prep<<<32896, 256, 0, stream>>>(x, wqkv, wout, cosp, sinp, xb, wqkvb, woutb, cs);
  gemm_qkv<<<768, 512, 0, stream>>>(xb, wqkvb, qkv, vt, cs);
  attn_fused<<<1024, 512, 0, stream>>>(qkv, vt, attn);
  gemm_out_k<<<256, 512, 0, stream>>>(attn, woutb, outp);
}

// Round 7
// 616.913 us; speedup vs baseline: 1.8910x; 1.0769x over previous
//
#include <hip/hip_runtime.h>
#include <cstdint>
#include <cstddef>

typedef unsigned short u16;
typedef __attribute__((ext_vector_type(8))) short bf16x8;   // 8 bf16 = 4 VGPRs
typedef __attribute__((ext_vector_type(4))) float f32x4;    // MFMA accumulator

#define DEVFN static __device__ __forceinline__

DEVFN u16 f2bf(float f) {
  unsigned u = __float_as_uint(f);
  unsigned r = (u + 0x7FFFu + ((u >> 16) & 1u)) >> 16;   // RTN-even
  return (u16)r;
}

// async global->LDS, 16B/lane. LDS dest = wave-uniform base + lane*16 (m104/m108).
DEVFN void gload16(const void* g, void* l) {
  __builtin_amdgcn_global_load_lds(
      (const __attribute__((address_space(1))) void*)g,
      (__attribute__((address_space(3))) void*)l, 16, 0, 0);
}

// counted waits + raw barrier (compiler memory fences keep LDS ops ordered)
#define WAITVM(n) asm volatile("s_waitcnt vmcnt(" #n ")" ::: "memory")
#define BARRIER() do { asm volatile("" ::: "memory"); \
                       __builtin_amdgcn_s_barrier();   \
                       asm volatile("" ::: "memory"); } while (0)
// Wave-internal LDS write->read fence: compiler order ("memory") + hw retirement
// (lgkmcnt 0) + sched pin (rule #18). Needed because cross-lane P round-trip is
// invisible to LLVM's per-lane alias analysis (R8 failure: hoisted ds_read).
#define FENCE_LDS() do { asm volatile("s_waitcnt lgkmcnt(0)" ::: "memory"); \
                         __builtin_amdgcn_sched_barrier(0); } while (0)

// ---------------- merged prep: converts + wqkv row-permute + cos/sin table ----------------
// wqkv q/k rows interleaved per head: d<64 -> 2d, d>=64 -> 2(d-64)+1  (QK^T invariant).
// cs[l*64+m] = (cos(l,m), sin(l,m))
__global__ void prep(const float* __restrict__ x, const float* __restrict__ wqkv,
                     const float* __restrict__ wout, const float* __restrict__ cosp,
                     const float* __restrict__ sinp, u16* __restrict__ xb,
                     u16* __restrict__ wqkvb, u16* __restrict__ woutb,
                     float2* __restrict__ cs) {
  constexpr int X4 = 4194304;      // x elems/4
  constexpr int W4 = 3145728;      // wqkv elems/4
  constexpr int O4 = 1048576;      // wout elems/4
  int i = blockIdx.x * blockDim.x + threadIdx.x;
  if (i < X4) {
    float4 v = ((const float4*)x)[i];
    unsigned long long w = (unsigned long long)f2bf(v.x)
        | ((unsigned long long)f2bf(v.y) << 16)
        | ((unsigned long long)f2bf(v.z) << 32)
        | ((unsigned long long)f2bf(v.w) << 48);
    *(unsigned long long*)(xb + (size_t)i * 4) = w;
  } else if (i < X4 + W4) {
    int j = i - X4;
    int base = j * 4;
    int e = base >> 11, col = base & 2047;
    int e2;
    if (e < 4096) {
      int part = e >> 11, loc = e & 2047;
      int h = loc >> 7, d = loc & 127;
      int d2 = (d < 64) ? 2 * d : 2 * (d - 64) + 1;
      e2 = part * 2048 + h * 128 + d2;
    } else {
      e2 = e;                      // v rows unpermuted
    }
    float4 v = *(const float4*)&wqkv[(size_t)base];
    unsigned long long w = (unsigned long long)f2bf(v.x)
        | ((unsigned long long)f2bf(v.y) << 16)
        | ((unsigned long long)f2bf(v.z) << 32)
        | ((unsigned long long)f2bf(v.w) << 48);
    *(unsigned long long*)(wqkvb + (size_t)e2 * 2048 + col) = w;
  } else if (i < X4 + W4 + O4) {
    int j = i - X4 - W4;
    float4 v = ((const float4*)wout)[j];
    unsigned long long w = (unsigned long long)f2bf(v.x)
        | ((unsigned long long)f2bf(v.y) << 16)
        | ((unsigned long long)f2bf(v.z) << 32)
        | ((unsigned long long)f2bf(v.w) << 48);
    *(unsigned long long*)(woutb + (size_t)j * 4) = w;
  } else {
    int k = i - X4 - W4 - O4;      // < 32768
    int ld4 = k * 4;
#pragma unroll
    for (int u = 0; u < 4; u++) {
      int ld = ld4 + u;
      int l = ld >> 6, d = ld & 63;
      cs[ld] = make_float2(cosp[(size_t)l * 128 + d], sinp[(size_t)l * 128 + d]);
    }
  }
}

// ================= 256x256 8-phase GEMM core (T3+T4+T5 on verified layouts) ==============
// BM=BN=256, BK=64, 512 thr = 8 waves (2M x 4N), wave output 128x64 = acc[8][4].
// LDS: A[2][256*64] + B[2][256*64] bf16 = 128 KB, double-buffered by K-tile parity.
// Rows are 64 elems (128B), chunk XOR swizzle key = row&7 (both staged-source and read
// sides -> conflict-free b128 reads, gload_lds-compatible: LDS linear, source pre-swizzled).
// Schedule per K-tile t (4 phases), staging tile t+1 one tile ahead:
//   ph1: issue B(t+1,h0)[2 ops]  vmcnt(5)  bar  read Ball+Aq0, 16 MFMA
//   ph2: issue B(t+1,h1)[2]      vmcnt(6)  bar  read Aq1,      16 MFMA
//   ph3: issue Aq0,Aq1(t+1)[2]   vmcnt(7)  bar  read Aq2,      16 MFMA
//   ph4: issue Aq2,Aq3(t+1)[2]   vmcnt(8)  bar  read Aq3,      16 MFMA
// Ledger (per-wave outstanding VMEM ops) verified steady-state; loads never drain to 0.
// Last tile peeled with vmcnt 3/2/1/0 and no issues.
enum { M_F32OUT = 0, M_ROPE = 1, M_VT = 2 };

DEVFN bf16x8 rdfrag(const u16* buf, int row, int chunk) {
  return *(const bf16x8*)&buf[row * 64 + (((chunk ^ (row & 7)) & 7) << 3)];
}

template <int MODE, int Q>
DEVFN void phase_mfma(const u16* Ac, const u16* Bc, int wm, int wn, int quad, int l16,
                      bf16x8 (&bfr)[4][2], f32x4 (&acc)[8][4]) {
  if (Q == 0) {
#pragma unroll
    for (int j = 0; j < 4; j++)
#pragma unroll
      for (int kk = 0; kk < 2; kk++)
        bfr[j][kk] = rdfrag(Bc, wn * 64 + j * 16 + l16, kk * 4 + quad);
  }
  bf16x8 af[2][2];
#pragma unroll
  for (int i2 = 0; i2 < 2; i2++)
#pragma unroll
    for (int kk = 0; kk < 2; kk++)
      af[i2][kk] = rdfrag(Ac, wm * 128 + (Q * 2 + i2) * 16 + l16, kk * 4 + quad);
  __builtin_amdgcn_s_setprio(1);
#pragma unroll
  for (int kk = 0; kk < 2; kk++)
#pragma unroll
    for (int i2 = 0; i2 < 2; i2++)
#pragma unroll
      for (int j = 0; j < 4; j++) {
        if (MODE == M_VT)
          acc[Q * 2 + i2][j] = __builtin_amdgcn_mfma_f32_16x16x32_bf16(
              bfr[j][kk], af[i2][kk], acc[Q * 2 + i2][j], 0, 0, 0);
        else
          acc[Q * 2 + i2][j] = __builtin_amdgcn_mfma_f32_16x16x32_bf16(
              af[i2][kk], bfr[j][kk], acc[Q * 2 + i2][j], 0, 0, 0);
      }
  __builtin_amdgcn_s_setprio(0);
}

template <int MODE>
DEVFN void gemm256_core(const u16* __restrict__ A, const u16* __restrict__ Bt,
                        void* __restrict__ Cv, const float2* __restrict__ cs,
                        int N, int m0, int n0, u16* As, u16* Bs) {
  int tid = threadIdx.x;
  int wv = tid >> 6, lane = tid & 63, quad = lane >> 4, l16 = lane & 15;
  int wm = wv >> 2, wn = wv & 3;

  // per-thread pre-swizzled global source pointers (advance by k elems per tile)
  const u16* pB[2][2];
  const u16* pA[4];
#pragma unroll
  for (int h = 0; h < 2; h++)
#pragma unroll
    for (int o = 0; o < 2; o++) {
      int r = h * 128 + o * 64 + wv * 8 + (lane >> 3);
      int ck = (lane & 7) ^ (r & 7);
      pB[h][o] = Bt + (size_t)(n0 + r) * 2048 + ck * 8;
    }
#pragma unroll
  for (int q = 0; q < 4; q++) {
    int rb = (wv < 4) ? (q * 32 + wv * 8) : (128 + q * 32 + (wv - 4) * 8);
    int r = rb + (lane >> 3);
    int ck = (lane & 7) ^ (r & 7);
    pA[q] = A + (size_t)(m0 + r) * 2048 + ck * 8;
  }

#define STAGE_B(h, buf, kk) do {                                    \
    int rb0_ = (h) * 128 + wv * 8;                                  \
    gload16(pB[h][0] + (kk), &(buf)[rb0_ * 64]);                    \
    gload16(pB[h][1] + (kk), &(buf)[(rb0_ + 64) * 64]); } while (0)
#define STAGE_A(q, buf, kk) do {                                    \
    int rb_ = ((wv < 4) ? ((q) * 32 + wv * 8)                       \
                        : (128 + (q) * 32 + (wv - 4) * 8));         \
    gload16(pA[q] + (kk), &(buf)[rb_ * 64]); } while (0)

  f32x4 acc[8][4] = {};
  bf16x8 bfr[4][2];

  // prologue: stage tile 0 into buffer 0 (issue order matches the ledger)
  STAGE_B(0, Bs, 0);
  STAGE_B(1, Bs, 0);
  STAGE_A(0, As, 0);
  STAGE_A(1, As, 0);
  STAGE_A(2, As, 0);
  STAGE_A(3, As, 0);

  for (int t = 0; t < 31; t++) {
    const u16* Ac = As + (t & 1) * 16384;
    const u16* Bc = Bs + (t & 1) * 16384;
    u16* An = As + ((t + 1) & 1) * 16384;
    u16* Bn = Bs + ((t + 1) & 1) * 16384;
    int kn = (t + 1) * 64;
    STAGE_B(0, Bn, kn);
    WAITVM(5); BARRIER();
    phase_mfma<MODE, 0>(Ac, Bc, wm, wn, quad, l16, bfr, acc);
    STAGE_B(1, Bn, kn);
    WAITVM(6); BARRIER();
    phase_mfma<MODE, 1>(Ac, Bc, wm, wn, quad, l16, bfr, acc);
    STAGE_A(0, An, kn);
    STAGE_A(1, An, kn);
    WAITVM(7); BARRIER();
    phase_mfma<MODE, 2>(Ac, Bc, wm, wn, quad, l16, bfr, acc);
    STAGE_A(2, An, kn);
    STAGE_A(3, An, kn);
    WAITVM(8); BARRIER();
    phase_mfma<MODE, 3>(Ac, Bc, wm, wn, quad, l16, bfr, acc);
  }
  {  // last tile (parity 1), no prefetch: drain 3/2/1/0
    const u16* Ac = As + 16384;
    const u16* Bc = Bs + 16384;
    WAITVM(3); BARRIER();
    phase_mfma<MODE, 0>(Ac, Bc, wm, wn, quad, l16, bfr, acc);
    WAITVM(2); BARRIER();
    phase_mfma<MODE, 1>(Ac, Bc, wm, wn, quad, l16, bfr, acc);
    WAITVM(1); BARRIER();
    phase_mfma<MODE, 2>(Ac, Bc, wm, wn, quad, l16, bfr, acc);
    WAITVM(0); BARRIER();
    phase_mfma<MODE, 3>(Ac, Bc, wm, wn, quad, l16, bfr, acc);
  }
#undef STAGE_B
#undef STAGE_A

  // ---- epilogue: C/D layout col = lane&15, row = quad*4 + reg (m89/m91 verified) ----
  if (MODE == M_F32OUT) {
    float* C = (float*)Cv;
#pragma unroll
    for (int i = 0; i < 8; i++)
#pragma unroll
      for (int r = 0; r < 4; r++) {
        size_t row = (size_t)(m0 + wm * 128 + i * 16 + quad * 4 + r);
#pragma unroll
        for (int j = 0; j < 4; j++)
          C[row * N + (n0 + wn * 64 + j * 16 + l16)] = acc[i][j][r];
      }
  } else if (MODE == M_ROPE) {
    constexpr float QSCALE = 1.4426950408889634f * 0.08838834764831845f;
    const float scale = (n0 >> 11) ? 1.0f : QSCALE;   // q gets log2e/sqrt(128)
    u16* C = (u16*)Cv;
#pragma unroll
    for (int i = 0; i < 8; i++)
#pragma unroll
      for (int r = 0; r < 4; r++) {
        int row = m0 + wm * 128 + i * 16 + quad * 4 + r;
        int l = row & 2047;
#pragma unroll
        for (int j = 0; j < 4; j++) {
          int col = n0 + wn * 64 + j * 16 + l16;
          int dm = (col & 127) >> 1;
          float2 csv = cs[l * 64 + dm];
          float v = acc[i][j][r];
          float pv = __shfl_xor(v, 1);                 // partner lane (col^1)
          float sg = (l16 & 1) ? csv.y : -csv.y;       // even: -sin, odd: +sin
          C[(size_t)row * 4096 + col] = f2bf((v * csv.x + pv * sg) * scale);
        }
      }
  } else {
    // VT: swapped operands -> acc holds C^T; row = v-channel, col = token. vt[bh][d][l].
    u16* vt = (u16*)Cv;
#pragma unroll
    for (int j = 0; j < 4; j++)
#pragma unroll
      for (int r = 0; r < 4; r++) {
        int vch = n0 + wn * 64 + j * 16 + quad * 4 + r;   // 0..2047
        int h = vch >> 7, d = vch & 127;
#pragma unroll
        for (int i = 0; i < 8; i++) {
          int token = m0 + wm * 128 + i * 16 + l16;
          int b = token >> 11, lloc = token & 2047;
          vt[((size_t)(b * 16 + h)) * 262144 + (size_t)d * 2048 + lloc] =
              f2bf(acc[i][j][r]);
        }
      }
  }
}

// Merged QKV GEMM: bx<16 -> RoPE epilogue into qkv (stride 4096); bx>=16 -> V^T.
// XCD y-striping: each XCD owns a 4-row stripe of M-tiles (A rows L2-resident).
__global__ __launch_bounds__(512, 2) void gemm_qkv(const u16* __restrict__ xb,
                                                   const u16* __restrict__ wqkvb,
                                                   u16* __restrict__ qkvo,
                                                   u16* __restrict__ vto,
                                                   const float2* __restrict__ cs) {
  __shared__ u16 As[32768];
  __shared__ u16 Bs[32768];
  int id = blockIdx.x;
  int xcd = id & 7, sub = id >> 3;      // sub 0..95
  int bx = sub % 24, by = xcd * 4 + sub / 24;
  if (bx < 16)
    gemm256_core<M_ROPE>(xb, wqkvb, qkvo, cs, 0, by * 256, bx * 256, As, Bs);
  else
    gemm256_core<M_VT>(xb, wqkvb + (size_t)4096 * 2048, vto, nullptr, 0,
                       by * 256, (bx - 16) * 256, As, Bs);
}

__global__ __launch_bounds__(512, 2) void gemm_out_k(const u16* __restrict__ A,
                                                     const u16* __restrict__ Bt,
                                                     float* __restrict__ C) {
  __shared__ u16 As[32768];
  __shared__ u16 Bs[32768];
  int id = blockIdx.x;
  int xcd = id & 7, sub = id >> 3;      // sub 0..31
  int bx = sub % 8, by = xcd * 4 + sub / 8;
  gemm256_core<M_F32OUT>(A, Bt, C, nullptr, 2048, by * 256, bx * 256, As, Bs);
}

// ---------------- fused flash attention (fixed-base softmax, no online max) ----------------
// R9 = R8 geometry + correctness fixes. 256 thr / 4 waves / 32 q-rows per wave (each
// K/V fragment read feeds TWO row-tiles), KVBLK=32, double-buffered K (2x8KB) +
// V (2x8KB) + padded P (128 x 40 = 10KB) = 43KB LDS -> 3 blocks/CU, 12 waves/CU.
// R8 failure root-cause (theory): padded-linear P indices let LLVM prove per-lane
// write/read disjointness and hoist the cross-lane pf ds_read above the P ds_writes
// (R6's XOR-swizzled indices were opaque -> no reorder). Fix: FENCE_LDS between the
// P-write loop and the pf reads. Also reverted fexp2 raw asm -> exp2f (proven).
DEVFN int swz(int row, int chunk)   { return row * 128 + ((chunk ^ (row & 15)) << 3); } // 256B rows
DEVFN int swz32(int row, int chunk) { return row * 32  + (((chunk ^ (row & 3)) & 3) << 3); } // 64B rows

__global__ __launch_bounds__(256, 3) void attn_fused(const u16* __restrict__ qkv,
                                                     const u16* __restrict__ vt,
                                                     u16* __restrict__ out) {
  // S layout (u16 units): [0,4096)=Kb0 [4096,8192)=Kb1
  //                       [8192,12288)=Vb0 [12288,16384)=Vb1
  //                       [16384,21504)=P (128 rows x 40 elems, 80B stride: bank-spread)
  __shared__ u16 S[21504];                     // 43008 B
  u16* const Pb = S + 16384;
  int tid = threadIdx.x;
  int wv = tid >> 6, lane = tid & 63, quad = lane >> 4, l16 = lane & 15;
  int id = blockIdx.x;
  int xcd = id & 7, sub = id >> 3;             // sub 0..127
  int bh = ((sub >> 4) << 3) | xcd;            // 8 bh per XCD, all 16 qtiles local
  int qt = sub & 15;
  int b = bh >> 4, hh = bh & 15;
  const u16* qptr = qkv + (size_t)b * 2048 * 4096 + hh * 128;
  const u16* kptr = qptr + 2048;
  const u16* vptr = vt + (size_t)bh * 262144;
  int q0 = qt * 128;

  // ---- Q staging: 128 rows x 256B through S[0..16384), then pull to regs ----
#pragma unroll
  for (int j = 0; j < 8; j++) {
    int rb = wv * 4 + j * 16;
    int r = rb + (lane >> 4);
    int ck = (lane & 15) ^ (r & 15);
    gload16(&qptr[(size_t)(q0 + r) * 4096 + ck * 8], &S[rb * 128]);
  }
  __syncthreads();
  bf16x8 qf[2][4];
#pragma unroll
  for (int hf = 0; hf < 2; hf++)
#pragma unroll
    for (int ks = 0; ks < 4; ks++)
      qf[hf][ks] = *(const bf16x8*)&S[swz(wv * 32 + hf * 16 + l16, ks * 4 + quad)];
  __syncthreads();                             // qf reads done before kt=0 staging

  f32x4 o[2][8] = {};
  float l[2][4] = {{0.f, 0.f, 0.f, 0.f}, {0.f, 0.f, 0.f, 0.f}};

  // prologue: stage kt=0 into Kb0/Vb0 (K: 32 rows x 256B; V^T: 128 rows x 64B)
#pragma unroll
  for (int j = 0; j < 2; j++) {
    int rbk = wv * 4 + j * 16;
    int rk = rbk + (lane >> 4);
    int ckk = (lane & 15) ^ (rk & 15);
    gload16(&kptr[(size_t)rk * 4096 + ckk * 8], &S[rbk * 128]);
    int rbv = wv * 16 + j * 64;
    int rv = rbv + (lane >> 2);
    int ckv = (lane & 3) ^ (rv & 3);
    gload16(&vptr[(size_t)rv * 2048 + ckv * 8], &S[8192 + rbv * 32]);
  }

  for (int kt = 0; kt < 64; kt++) {
    int cur = kt & 1;
    const u16* Kc = S + cur * 4096;
    const u16* Vc = S + 8192 + cur * 4096;
    __syncthreads();   // auto vmcnt(0): drains cur-tile loads (1 iter old) + prior reads
    if (kt < 63) {     // prefetch kt+1 into the other buffer set
      int kk0 = (kt + 1) * 32;
      u16* kb = S + (cur ^ 1) * 4096;
      u16* vb = S + 8192 + (cur ^ 1) * 4096;
#pragma unroll
      for (int j = 0; j < 2; j++) {
        int rbk = wv * 4 + j * 16;
        int rk = rbk + (lane >> 4);
        int ckk = (lane & 15) ^ (rk & 15);
        gload16(&kptr[(size_t)(kk0 + rk) * 4096 + ckk * 8], &kb[rbk * 128]);
        int rbv = wv * 16 + j * 64;
        int rv = rbv + (lane >> 2);
        int ckv = (lane & 3) ^ (rv & 3);
        gload16(&vptr[(size_t)rv * 2048 + kk0 + ckv * 8], &vb[rbv * 32]);
      }
    }
    // S = Q K^T (scores in log2 domain via QSCALE folded into q).
    // One K-frag read feeds BOTH row-halves (the traffic halving).
    f32x4 s[2][2] = {};
#pragma unroll
    for (int ks = 0; ks < 4; ks++) {
#pragma unroll
      for (int nt = 0; nt < 2; nt++) {
        bf16x8 bfr = *(const bf16x8*)&Kc[swz(nt * 16 + l16, ks * 4 + quad)];
        s[0][nt] = __builtin_amdgcn_mfma_f32_16x16x32_bf16(qf[0][ks], bfr, s[0][nt], 0, 0, 0);
        s[1][nt] = __builtin_amdgcn_mfma_f32_16x16x32_bf16(qf[1][ks], bfr, s[1][nt], 0, 0, 0);
      }
    }
    // fixed-base softmax: p = exp2(s); lane-local row-sum; P -> padded private buffer
#pragma unroll
    for (int hf = 0; hf < 2; hf++)
#pragma unroll
      for (int nt = 0; nt < 2; nt++)
#pragma unroll
        for (int r = 0; r < 4; r++) {
          float p = exp2f(s[hf][nt][r]);
          l[hf][r] += p;
          int row = wv * 32 + hf * 16 + quad * 4 + r;
          int col = nt * 16 + l16;
          Pb[row * 40 + col] = f2bf(p);
        }
    // cross-lane P round-trip: force all P ds_writes to retire before pf ds_reads
    // (wave-private rows -> no cross-wave barrier needed; see R9 header comment)
    FENCE_LDS();
    // O += P V  (Vc holds V^T: rows = d, cols = 32 keys; K=32 -> one MFMA per tile).
    // One V-frag read feeds BOTH row-halves.
    {
      bf16x8 pf0 = *(const bf16x8*)&Pb[(wv * 32 + l16) * 40 + quad * 8];
      bf16x8 pf1 = *(const bf16x8*)&Pb[(wv * 32 + 16 + l16) * 40 + quad * 8];
#pragma unroll
      for (int nt = 0; nt < 8; nt++) {
        bf16x8 vf = *(const bf16x8*)&Vc[swz32(nt * 16 + l16, quad)];
        o[0][nt] = __builtin_amdgcn_mfma_f32_16x16x32_bf16(pf0, vf, o[0][nt], 0, 0, 0);
        o[1][nt] = __builtin_amdgcn_mfma_f32_16x16x32_bf16(pf1, vf, o[1][nt], 0, 0, 0);
      }
    }
  }
  // epilogue: reduce l across the 16 col-lanes once, divide, store bf16
#pragma unroll
  for (int hf = 0; hf < 2; hf++)
#pragma unroll
    for (int r = 0; r < 4; r++)
#pragma unroll
      for (int off = 1; off < 16; off <<= 1) l[hf][r] += __shfl_xor(l[hf][r], off, 16);
  u16* obase = out + ((size_t)b * 2048 + q0) * 2048 + hh * 128;
#pragma unroll
  for (int hf = 0; hf < 2; hf++)
#pragma unroll
    for (int r = 0; r < 4; r++) {
      float inv = 1.0f / l[hf][r];
      int row = wv * 32 + hf * 16 + quad * 4 + r;
#pragma unroll
      for (int nt = 0; nt < 8; nt++)
        obase[(size_t)row * 2048 + nt * 16 + l16] = f2bf(o[hf][nt][r] * inv);
    }
}

// ---------------- launch ----------------
extern "C" void kernel_launch(void* const* d_in, const int* in_sizes, int n_in,
                              void* d_out, int out_size, void* d_ws, size_t ws_size,
                              hipStream_t stream) {
  const float* x    = (const float*)d_in[0];   // [4,2048,2048]
  const float* cosp = (const float*)d_in[1];   // [2048,128]
  const float* sinp = (const float*)d_in[2];   // [2048,128]
  const float* wqkv = (const float*)d_in[3];   // [6144,2048]
  const float* wout = (const float*)d_in[4];   // [2048,2048]
  float* outp = (float*)d_out;                 // [4,2048,2048] fp32

  u16* ws    = (u16*)d_ws;
  u16* xb    = ws;                     // 16,777,216 elems (dead after gemm_qkv; reused)
  u16* wqkvb = xb + 16777216;          // 12,582,912 (row-permuted q/k)
  u16* woutb = wqkvb + 12582912;       //  4,194,304
  u16* qkv   = woutb + 4194304;        // 33,554,432 (q,k only; row stride 4096)
  u16* vt    = qkv + 33554432;         // 16,777,216
  float2* cs = (float2*)(vt + 16777216); // 131,072 float2 = 1 MB
  u16* attn  = xb;                     // alias: xb dead after gemm_qkv

  prep<<<32896, 256, 0, stream>>>(x, wqkv, wout, cosp, sinp, xb, wqkvb, woutb, cs);
  gemm_qkv<<<768, 512, 0, stream>>>(xb, wqkvb, qkv, vt, cs);
  attn_fused<<<1024, 256, 0, stream>>>(qkv, vt, attn);
  gemm_out_k<<<256, 512, 0, stream>>>(attn, woutb, outp);
}